// Round 19
// baseline (288.942 us; speedup 1.0000x reference)
//
#include <hip/hip_runtime.h>

#define BB 8
#define LL 512
#define HH 8
#define BIGV (1e9f)

typedef unsigned short u16;
typedef __attribute__((ext_vector_type(8))) short bf16x8;
typedef __attribute__((ext_vector_type(4))) short s16x4;
typedef __attribute__((ext_vector_type(4))) float f32x4;

#define MFMA(a,b,c) __builtin_amdgcn_mfma_f32_16x16x32_bf16(a,b,c,0,0,0)

__device__ __forceinline__ u16 f2b(float f){
  unsigned u = __float_as_uint(f);
  u = (u + 0x7fffu + ((u>>16)&1u)) >> 16;
  return (u16)u;
}
__device__ __forceinline__ float b2f(u16 s){ return __uint_as_float(((unsigned)s)<<16); }
__device__ __forceinline__ bf16x8 ldb8(const u16* p){ return *(const bf16x8*)p; }
__device__ __forceinline__ s16x4 ld4nt(const u16* p){ return __builtin_nontemporal_load((const s16x4*)p); }
__device__ __forceinline__ void st4nt(u16* p, s16x4 v){ __builtin_nontemporal_store(v, (s16x4*)p); }
__device__ __forceinline__ void stb8nt(u16* p, bf16x8 v){ __builtin_nontemporal_store(v, (bf16x8*)p); }

__device__ __forceinline__ float g16_sum(float v){
  v += __shfl_xor(v,1,64); v += __shfl_xor(v,2,64);
  v += __shfl_xor(v,4,64); v += __shfl_xor(v,8,64);
  return v;
}

// ---- tables: T4t[c][b][a], Tt2[c][a][b], Gt[a][j], Gt2[j][a] ----
__global__ void kp_prep(const float* __restrict__ T, const float* __restrict__ gw,
                        u16* __restrict__ T4t, u16* __restrict__ Tt2,
                        u16* __restrict__ Gt, u16* __restrict__ Gt2){
  int idx = blockIdx.x*256 + threadIdx.x;   // < 32768
  { int c=idx>>12, b=(idx>>6)&63, a=idx&63; T4t[idx] = f2b(T[(a*64+b)*8+c]); }
  { int c=idx>>12, a=(idx>>6)&63, b=idx&63; Tt2[idx] = f2b(T[(a*64+b)*8+c]); }
  if(idx < 4096){
    int a=idx>>6, j=idx&63;
    Gt[idx]  = f2b(gw[j*64+a]);   // Gt[a][j]
    Gt2[idx] = f2b(gw[idx]);      // Gt2[j][a]
  }
}

// ---- kCA: fused [new_qz] + [row softmax] + [P2/Mg] + [t1b/t1t/t2t production] ----
__global__ __launch_bounds__(512) void kCA(const float* __restrict__ x, const int* __restrict__ mask,
      const u16* __restrict__ miP, const u16* __restrict__ mjP, const float* __restrict__ MgF_in,
      float* __restrict__ unary, float* __restrict__ mf,
      const u16* __restrict__ Gt2, const u16* __restrict__ Gt,
      const u16* __restrict__ T4t, const u16* __restrict__ Tt2,
      u16* __restrict__ qzb, float* __restrict__ MgF_out, float* __restrict__ out,
      u16* __restrict__ t1b, u16* __restrict__ t1t, u16* __restrict__ t2t, int mode){
  __shared__ u16 qlds[16*72];
  __shared__ u16 P2s[16*72];
  __shared__ float red2[16*4];
  int bid = blockIdx.x; int z = bid & 7, itile = bid >> 3;   // z-affine for XCD L2
  int t = threadIdx.x, lane = t&63, w = t>>6, l15 = lane&15, lhi = lane>>4;
  int rbase = z*LL + itile*16;
  if(t < 256){
    int row16 = t>>4, c4 = t&15;
    int rg = rbase + row16;
    float v[4]; float mk;
    if(mode == 0){
      mk = (mask[rg] != 0) ? 1.f : 0.f;
      if(c4 == 0) mf[rg] = mk;
      int pos = rg & (LL-1);
      #pragma unroll
      for(int k=0;k<4;k++){
        int d = c4*4 + k;
        float div = __expf(-(float)(d & ~1) * 0.14391156962f);  // ln(10000)/64
        float arg = (float)pos * div;
        float pe = (d & 1) ? cosf(arg) : sinf(arg);
        v[k] = (x[(size_t)rg*64 + d] + pe) * mk;
      }
      *(f32x4*)&unary[(size_t)rg*64 + c4*4] = (f32x4){v[0],v[1],v[2],v[3]};
    } else {
      mk = mf[rg];
      f32x4 acc = *(const f32x4*)&MgF_in[(size_t)rg*64 + c4*4];
      #pragma unroll
      for(int c=0;c<8;c++){
        s16x4 vv = ld4nt(&miP[(size_t)rg*512 + c*64 + c4*4]);
        acc[0]+=b2f((u16)vv[0]); acc[1]+=b2f((u16)vv[1]);
        acc[2]+=b2f((u16)vv[2]); acc[3]+=b2f((u16)vv[3]);
      }
      #pragma unroll
      for(int s=0;s<8;s++)
        #pragma unroll
        for(int c=0;c<8;c++){
          s16x4 vv = ld4nt(&mjP[(((size_t)(s*8+z))*LL + itile*16 + row16)*512 + c*64 + c4*4]);
          acc[0]+=b2f((u16)vv[0]); acc[1]+=b2f((u16)vv[1]);
          acc[2]+=b2f((u16)vv[2]); acc[3]+=b2f((u16)vv[3]);
        }
      f32x4 u0 = *(const f32x4*)&unary[(size_t)rg*64 + c4*4];
      #pragma unroll
      for(int k=0;k<4;k++) v[k] = (u0[k] + acc[k]) * mk;
    }
    if(mode == 2){
      *(f32x4*)&out[(size_t)rg*64 + c4*4] = (f32x4){v[0],v[1],v[2],v[3]};
    } else {
      // in-register row softmax: 16 lanes per row (group = c4)
      float mx = fmaxf(fmaxf(v[0],v[1]), fmaxf(v[2],v[3]));
      mx = fmaxf(mx, __shfl_xor(mx,1,64));
      mx = fmaxf(mx, __shfl_xor(mx,2,64));
      mx = fmaxf(mx, __shfl_xor(mx,4,64));
      mx = fmaxf(mx, __shfl_xor(mx,8,64));
      float s = 0.f;
      #pragma unroll
      for(int k=0;k<4;k++){ v[k] = __expf(v[k]-mx); s += v[k]; }
      s += __shfl_xor(s,1,64); s += __shfl_xor(s,2,64);
      s += __shfl_xor(s,4,64); s += __shfl_xor(s,8,64);
      float iv = mk / s;
      s16x4 q4 = { (short)f2b(v[0]*iv), (short)f2b(v[1]*iv),
                   (short)f2b(v[2]*iv), (short)f2b(v[3]*iv) };
      *(s16x4*)&qzb[(size_t)rg*64 + c4*4] = q4;
      *(s16x4*)&qlds[row16*72 + c4*4] = q4;
    }
  }
  if(mode == 2) return;                       // uniform: no barrier crossed
  __syncthreads();
  // ---- P2 = rowsoftmax(qz @ gw^T) (waves 0-3; fixed-max exp) ----
  float fv[4];
  if(t < 256){
    bf16x8 a0 = ldb8(&qlds[l15*72 + lhi*8]);
    bf16x8 a1 = ldb8(&qlds[l15*72 + lhi*8 + 32]);
    const u16* Br = Gt2 + (size_t)(w*16 + l15)*64 + lhi*8;
    f32x4 acc = {0.f,0.f,0.f,0.f};
    acc = MFMA(a0, ldb8(Br), acc);
    acc = MFMA(a1, ldb8(Br+32), acc);
    #pragma unroll
    for(int jj=0;jj<4;jj++){
      float e = __expf(acc[jj]);
      fv[jj] = e;
      float p = g16_sum(e);
      if(l15==0) red2[(lhi*4+jj)*4 + w] = p;
    }
  }
  __syncthreads();
  if(t < 256){
    #pragma unroll
    for(int jj=0;jj<4;jj++){
      int r = lhi*4+jj;
      float s = red2[r*4+0]+red2[r*4+1]+red2[r*4+2]+red2[r*4+3];
      float iv = 1.f/s;
      P2s[r*72 + w*16 + l15] = f2b(fv[jj]*iv);
    }
  }
  __syncthreads();
  if(t < 256){
    // ---- Mg[i,a] = sum_j P2[i,j] gw[j,a]; a-quadrant per wave ----
    bf16x8 a0 = ldb8(&P2s[l15*72 + lhi*8]);
    bf16x8 a1 = ldb8(&P2s[l15*72 + lhi*8 + 32]);
    const u16* Br = Gt + (size_t)(w*16 + l15)*64 + lhi*8;
    f32x4 acc = {0.f,0.f,0.f,0.f};
    acc = MFMA(a0, ldb8(Br), acc);
    acc = MFMA(a1, ldb8(Br+32), acc);
    #pragma unroll
    for(int jj=0;jj<4;jj++)
      MgF_out[((size_t)rbase + lhi*4 + jj)*64 + w*16 + l15] = acc[jj];
  }
  // ---- phase T (all 8 waves): t1b/t1t/t2t for this tile's 16 rows; wave w = c ----
  {
    int c = w;
    size_t zc = (size_t)z*8 + c;
    bf16x8 aq0 = ldb8(&qlds[l15*72 + lhi*8]);
    bf16x8 aq1 = ldb8(&qlds[l15*72 + lhi*8 + 32]);
    const u16* T4c = T4t + c*4096;
    const u16* Ttc = Tt2 + c*4096;
    #pragma unroll
    for(int s=0;s<4;s++){
      const u16* Bq = T4c + (s*16 + l15)*64 + lhi*8;
      bf16x8 tb0 = ldb8(Bq), tb1 = ldb8(Bq+32);
      const u16* Uq = Ttc + (s*16 + l15)*64 + lhi*8;
      bf16x8 ub0 = ldb8(Uq), ub1 = ldb8(Uq+32);
      f32x4 d1 = {0.f,0.f,0.f,0.f};               // t1[i][b]
      d1 = MFMA(aq0, tb0, d1);
      d1 = MFMA(aq1, tb1, d1);
      f32x4 d2 = {0.f,0.f,0.f,0.f};               // t1t[b][i]
      d2 = MFMA(tb0, aq0, d2);
      d2 = MFMA(tb1, aq1, d2);
      f32x4 d3 = {0.f,0.f,0.f,0.f};               // t2t[a][j]
      d3 = MFMA(ub0, aq0, d3);
      d3 = MFMA(ub1, aq1, d3);
      #pragma unroll
      for(int jj=0;jj<4;jj++){
        int r4 = lhi*4 + jj;
        t1b[(zc*LL + itile*16 + r4)*64 + s*16 + l15]  = f2b(d1[jj]);
        t1t[(zc*64 + s*16 + r4)*LL + itile*16 + l15]  = f2b(d2[jj]);
        t2t[(zc*64 + s*16 + r4)*LL + itile*16 + l15]  = f2b(d3[jj]);
      }
    }
  }
}

// ---- kF: no t2s (mi reads t2t from L2 directly; nt output stores keep the
// z-affine read set L2-resident). Per-wave ping-pong PpT (16x40). LDS 62.7KB
// -> 2 blocks/CU; grid 512 = (z,c,it<8), 2 panels/block so 2 blocks co-reside.
// Register profile identical to round 15/18 (no spill). ----
__global__ __launch_bounds__(1024) void kF(const u16* __restrict__ t1b, const u16* __restrict__ qzb,
        const u16* __restrict__ t1t, const u16* __restrict__ t2t, const float* __restrict__ mf,
        u16* __restrict__ miP, u16* __restrict__ mjP){
  extern __shared__ char smem[];
  u16*   Pp    = (u16*)smem;                   // [32][520]     33280 B (unnormalized exp)
  u16*   PpT   = (u16*)(smem + 33280);         // [16w][16][40] 20480 B (ping-pong, wave-local)
  float* redS2 = (float*)(smem + 53760);       // [2][32]         256 B (parity row-sums)
  u16*   stgm  = (u16*)(smem + 54016);         // [2][32][68]    8704 B (mi u16 halves; end 62720)
  u16*   stg   = (u16*)smem;                   // [256][72] dump 36864 B (reuses Pp+PpT)
  int bid = blockIdx.x;
  int z = bid&7, c = (bid>>3)&7, it = bid>>6;   // it < 8
  int zc = z*8 + c;
  int t = threadIdx.x, lane = t&63, w = t>>6, l15 = lane&15, lhi = lane>>4;
  int jc0 = w*32;                               // wave's j-slice
  int h = w>>3, wr = (w>>2)&1, wc = w&3;        // mi role (K-half h)
  if(t < 64) redS2[t] = 0.f;
  __syncthreads();
  float mfj[2];
  mfj[0] = mf[z*LL + jc0 + l15];
  mfj[1] = mf[z*LL + jc0 + 16 + l15];
  f32x4 mj[2][4];
  #pragma unroll
  for(int jt=0;jt<2;jt++)
    #pragma unroll
    for(int bt=0;bt<4;bt++) mj[jt][bt] = (f32x4){0.f,0.f,0.f,0.f};
  u16* PpTw = PpT + w*16*40;                    // wave-local ping-pong tile

  for(int ip=0; ip<2; ++ip){
    int i0g = it*64 + ip*32;
    int par = ip & 1;
    f32x4 S[2][2];
    #pragma unroll
    for(int rt=0;rt<2;rt++){ S[rt][0] = (f32x4){0,0,0,0}; S[rt][1] = (f32x4){0,0,0,0}; }
    #pragma unroll
    for(int rt=0;rt<2;rt++){
      const u16* Ar = t1b + ((size_t)zc*LL + i0g + rt*16 + l15)*64 + lhi*8;
      bf16x8 a0 = ldb8(Ar), a1 = ldb8(Ar+32);
      #pragma unroll
      for(int ct=0;ct<2;ct++){
        const u16* Br = qzb + ((size_t)z*LL + jc0 + ct*16 + l15)*64 + lhi*8;
        S[rt][ct] = MFMA(a0, ldb8(Br), S[rt][ct]);
        S[rt][ct] = MFMA(a1, ldb8(Br+32), S[rt][ct]);
      }
    }
    #pragma unroll
    for(int rt=0;rt<2;rt++)
      #pragma unroll
      for(int jj=0;jj<4;jj++){
        int rloc = rt*16 + lhi*4 + jj;
        int irow = i0g + rloc;
        float mfi = mf[z*LL + irow];
        float ps = 0.f;
        #pragma unroll
        for(int ct=0;ct<2;ct++){
          int jcol = jc0 + ct*16 + l15;
          float v = S[rt][ct][jj] - ((irow==jcol)?BIGV:0.f);
          float e = mfi * mfj[ct] * __expf(v);
          S[rt][ct][jj] = e; ps += e;
          Pp[rloc*520 + jcol] = f2b(e);        // unnormalized
        }
        ps = g16_sum(ps);
        if(l15 == 0) atomicAdd(&redS2[par*32 + rloc], ps);   // ds_add_f32, no-return
      }
    __syncthreads();                            // B1: Pp + redS2[par] complete
    if(t < 32) redS2[(par^1)*32 + t] = 0.f;     // zero other parity
    float ivv[2][4];
    #pragma unroll
    for(int rt=0;rt<2;rt++)
      #pragma unroll
      for(int jj=0;jj<4;jj++){
        float s = redS2[par*32 + rt*16 + lhi*4 + jj];
        ivv[rt][jj] = s > 0.f ? 1.f/s : 0.f;
      }
    // ---- mj: per ct-tile ping-pong transpose then MFMA (B = t1t, L2-hot) ----
    {
      bf16x8 bmj[4];
      #pragma unroll
      for(int bt=0;bt<4;bt++)
        bmj[bt] = ldb8(t1t + ((size_t)zc*64 + bt*16 + l15)*LL + i0g + lhi*8);
      #pragma unroll
      for(int ct=0;ct<2;ct++){
        #pragma unroll
        for(int rt=0;rt<2;rt++){
          s16x4 v4 = { (short)f2b(S[rt][ct][0]*ivv[rt][0]), (short)f2b(S[rt][ct][1]*ivv[rt][1]),
                       (short)f2b(S[rt][ct][2]*ivv[rt][2]), (short)f2b(S[rt][ct][3]*ivv[rt][3]) };
          *(s16x4*)&PpTw[l15*40 + rt*16 + lhi*4] = v4;
        }
        bf16x8 av = ldb8(PpTw + l15*40 + lhi*8);
        #pragma unroll
        for(int bt=0;bt<4;bt++) mj[ct][bt] = MFMA(av, bmj[bt], mj[ct][bt]);
      }
    }
    // ---- mi: K-half h; A = Pp (unnorm, LDS), B = t2t (global, L2-hot) ----
    {
      f32x4 mia = {0.f,0.f,0.f,0.f};
      const u16* Ab = Pp + (wr*16 + l15)*520 + h*256 + lhi*8;
      const u16* Bb = t2t + ((size_t)zc*64 + wc*16 + l15)*LL + h*256 + lhi*8;
      #pragma unroll
      for(int ks=0;ks<8;ks++)
        mia = MFMA(ldb8(Ab + ks*32), ldb8(Bb + ks*32), mia);
      #pragma unroll
      for(int jj=0;jj<4;jj++)
        stgm[(h*32 + wr*16 + lhi*4 + jj)*68 + wc*16 + l15] = f2b(mia[jj]*ivv[wr][jj]);
    }
    __syncthreads();                            // B2: stgm ready; Pp reads done
    if(t < 512){
      int r = t>>4, cc = t&15;
      s16x4 v0 = *(const s16x4*)&stgm[r*68 + cc*4];
      s16x4 v1 = *(const s16x4*)&stgm[(32+r)*68 + cc*4];
      s16x4 o = { (short)f2b(b2f((u16)v0[0])+b2f((u16)v1[0])),
                  (short)f2b(b2f((u16)v0[1])+b2f((u16)v1[1])),
                  (short)f2b(b2f((u16)v0[2])+b2f((u16)v1[2])),
                  (short)f2b(b2f((u16)v0[3])+b2f((u16)v1[3])) };
      st4nt(&miP[((size_t)z*LL + i0g + r)*512 + c*64 + cc*4], o);
    }
  }
  // ---- mj dump: 2 rounds of 256 j-rows via stg (reuses dead Pp/PpT) ----
  #pragma unroll
  for(int r2=0;r2<2;r2++){
    __syncthreads();
    if((w>>3) == r2){
      int jl = jc0 - r2*256;
      #pragma unroll
      for(int jt=0;jt<2;jt++)
        #pragma unroll
        for(int bt=0;bt<4;bt++)
          #pragma unroll
          for(int jj=0;jj<4;jj++)
            stg[(jl + jt*16 + lhi*4 + jj)*72 + bt*16 + l15] = f2b(mj[jt][bt][jj]);
    }
    __syncthreads();
    #pragma unroll
    for(int q=0;q<2;q++){
      int e = q*1024 + t;
      int j = e >> 3, ch = e & 7;
      stb8nt(&mjP[(((size_t)(it*8 + z))*LL + r2*256 + j)*512 + c*64 + ch*8],
             *(const bf16x8*)&stg[j*72 + ch*8]);
    }
  }
}

extern "C" void kernel_launch(void* const* d_in, const int* in_sizes, int n_in,
                              void* d_out, int out_size, void* d_ws, size_t ws_size,
                              hipStream_t stream) {
  const float* x       = (const float*)d_in[0];
  const int*   mask    = (const int*)d_in[1];
  const float* ternary = (const float*)d_in[2];
  const float* gw      = (const float*)d_in[3];
  float* out = (float*)d_out;

  const size_t NE = (size_t)BB*LL*64;          // 262144
  char* p = (char*)d_ws;
  auto alloc = [&](size_t bytes)->void*{
    void* r = (void*)p; p += (bytes + 255) & ~(size_t)255; return r;
  };
  float* unary   = (float*)alloc(NE*4);
  float* mf      = (float*)alloc((size_t)BB*LL*4);
  u16*   qzb     = (u16*)alloc(NE*2);
  u16*   t1b     = (u16*)alloc((size_t)BB*HH*LL*64*2);   // 4.2 MB
  u16*   t1t     = (u16*)alloc((size_t)BB*HH*LL*64*2);   // 4.2 MB
  u16*   t2t     = (u16*)alloc((size_t)BB*HH*LL*64*2);   // 4.2 MB
  float* MgF     = (float*)alloc(NE*4);                  // 1 MB
  u16*   miP     = (u16*)alloc((size_t)BB*LL*512*2);     // 4.2 MB
  u16*   mjP     = (u16*)alloc((size_t)64*LL*512*2);     // 33.5 MB (8 it-partials)
  u16*   T4t     = (u16*)alloc(32768*2);
  u16*   Tt2     = (u16*)alloc(32768*2);
  u16*   Gt      = (u16*)alloc(4096*2);
  u16*   Gt2     = (u16*)alloc(4096*2);

  const int KF_LDS = 62720;  // Pp 33280 + PpT 20480 + redS2 256 + stgm 8704
  hipFuncSetAttribute(reinterpret_cast<const void*>(kF),
                      hipFuncAttributeMaxDynamicSharedMemorySize, KF_LDS);

  kp_prep<<<128, 256, 0, stream>>>(ternary, gw, T4t, Tt2, Gt, Gt2);
  kCA<<<256, 512, 0, stream>>>(x, mask, miP, mjP, MgF, unary, mf, Gt2, Gt,
                               T4t, Tt2, qzb, MgF, out, t1b, t1t, t2t, 0);
  for(int it=0; it<4; ++it){
    kF<<<512, 1024, KF_LDS, stream>>>(t1b, qzb, t1t, t2t, mf, miP, mjP);
    kCA<<<256, 512, 0, stream>>>(x, mask, miP, mjP, MgF, unary, mf, Gt2, Gt,
                                 T4t, Tt2, qzb, MgF, out, t1b, t1t, t2t, (it==3) ? 2 : 1);
  }
}

// Round 20
// 208.130 us; speedup vs baseline: 1.3883x; 1.3883x over previous
//
#include <hip/hip_runtime.h>

#define BB 8
#define LL 512
#define HH 8
#define BIGV (1e9f)

typedef unsigned short u16;
typedef __attribute__((ext_vector_type(8))) short bf16x8;
typedef __attribute__((ext_vector_type(4))) short s16x4;
typedef __attribute__((ext_vector_type(4))) float f32x4;

#define MFMA(a,b,c) __builtin_amdgcn_mfma_f32_16x16x32_bf16(a,b,c,0,0,0)

__device__ __forceinline__ u16 f2b(float f){
  unsigned u = __float_as_uint(f);
  u = (u + 0x7fffu + ((u>>16)&1u)) >> 16;
  return (u16)u;
}
__device__ __forceinline__ float b2f(u16 s){ return __uint_as_float(((unsigned)s)<<16); }
__device__ __forceinline__ bf16x8 ldb8(const u16* p){ return *(const bf16x8*)p; }
__device__ __forceinline__ s16x4 ld4nt(const u16* p){ return __builtin_nontemporal_load((const s16x4*)p); }

__device__ __forceinline__ float g16_sum(float v){
  v += __shfl_xor(v,1,64); v += __shfl_xor(v,2,64);
  v += __shfl_xor(v,4,64); v += __shfl_xor(v,8,64);
  return v;
}

// ---- tables: T4t[c][b][a], Tt2[c][a][b], Gt[a][j], Gt2[j][a] ----
__global__ void kp_prep(const float* __restrict__ T, const float* __restrict__ gw,
                        u16* __restrict__ T4t, u16* __restrict__ Tt2,
                        u16* __restrict__ Gt, u16* __restrict__ Gt2){
  int idx = blockIdx.x*256 + threadIdx.x;   // < 32768
  { int c=idx>>12, b=(idx>>6)&63, a=idx&63; T4t[idx] = f2b(T[(a*64+b)*8+c]); }
  { int c=idx>>12, a=(idx>>6)&63, b=idx&63; Tt2[idx] = f2b(T[(a*64+b)*8+c]); }
  if(idx < 4096){
    int a=idx>>6, j=idx&63;
    Gt[idx]  = f2b(gw[j*64+a]);   // Gt[a][j]
    Gt2[idx] = f2b(gw[idx]);      // Gt2[j][a]
  }
}

// ---- kCA: fused [new_qz] + [row softmax] + [P2/Mg] + [t1b/t1t/t2t production]
// 512 threads: front (t<256) as before; phase T uses all 8 waves (wave w = channel c)
// to compute the k2 work for this tile's 16 rows — k2 kernel is eliminated.
__global__ __launch_bounds__(512) void kCA(const float* __restrict__ x, const int* __restrict__ mask,
      const u16* __restrict__ miP, const u16* __restrict__ mjP, const float* __restrict__ MgF_in,
      float* __restrict__ unary, float* __restrict__ mf,
      const u16* __restrict__ Gt2, const u16* __restrict__ Gt,
      const u16* __restrict__ T4t, const u16* __restrict__ Tt2,
      u16* __restrict__ qzb, float* __restrict__ MgF_out, float* __restrict__ out,
      u16* __restrict__ t1b, u16* __restrict__ t1t, u16* __restrict__ t2t, int mode){
  __shared__ u16 qlds[16*72];
  __shared__ u16 P2s[16*72];
  __shared__ float red2[16*4];
  int bid = blockIdx.x; int z = bid & 7, itile = bid >> 3;   // z-affine for XCD L2
  int t = threadIdx.x, lane = t&63, w = t>>6, l15 = lane&15, lhi = lane>>4;
  int rbase = z*LL + itile*16;
  if(t < 256){
    int row16 = t>>4, c4 = t&15;
    int rg = rbase + row16;
    float v[4]; float mk;
    if(mode == 0){
      mk = (mask[rg] != 0) ? 1.f : 0.f;
      if(c4 == 0) mf[rg] = mk;
      int pos = rg & (LL-1);
      #pragma unroll
      for(int k=0;k<4;k++){
        int d = c4*4 + k;
        float div = __expf(-(float)(d & ~1) * 0.14391156962f);  // ln(10000)/64
        float arg = (float)pos * div;
        float pe = (d & 1) ? cosf(arg) : sinf(arg);
        v[k] = (x[(size_t)rg*64 + d] + pe) * mk;
      }
      *(f32x4*)&unary[(size_t)rg*64 + c4*4] = (f32x4){v[0],v[1],v[2],v[3]};
    } else {
      mk = mf[rg];
      f32x4 acc = *(const f32x4*)&MgF_in[(size_t)rg*64 + c4*4];
      #pragma unroll
      for(int c=0;c<8;c++){
        s16x4 vv = ld4nt(&miP[(size_t)rg*512 + c*64 + c4*4]);
        acc[0]+=b2f((u16)vv[0]); acc[1]+=b2f((u16)vv[1]);
        acc[2]+=b2f((u16)vv[2]); acc[3]+=b2f((u16)vv[3]);
      }
      #pragma unroll
      for(int s=0;s<4;s++)
        #pragma unroll
        for(int c=0;c<8;c++){
          s16x4 vv = ld4nt(&mjP[(((size_t)(s*8+z))*LL + itile*16 + row16)*512 + c*64 + c4*4]);
          acc[0]+=b2f((u16)vv[0]); acc[1]+=b2f((u16)vv[1]);
          acc[2]+=b2f((u16)vv[2]); acc[3]+=b2f((u16)vv[3]);
        }
      f32x4 u0 = *(const f32x4*)&unary[(size_t)rg*64 + c4*4];
      #pragma unroll
      for(int k=0;k<4;k++) v[k] = (u0[k] + acc[k]) * mk;
    }
    if(mode == 2){
      *(f32x4*)&out[(size_t)rg*64 + c4*4] = (f32x4){v[0],v[1],v[2],v[3]};
    } else {
      // in-register row softmax: 16 lanes per row (group = c4)
      float mx = fmaxf(fmaxf(v[0],v[1]), fmaxf(v[2],v[3]));
      mx = fmaxf(mx, __shfl_xor(mx,1,64));
      mx = fmaxf(mx, __shfl_xor(mx,2,64));
      mx = fmaxf(mx, __shfl_xor(mx,4,64));
      mx = fmaxf(mx, __shfl_xor(mx,8,64));
      float s = 0.f;
      #pragma unroll
      for(int k=0;k<4;k++){ v[k] = __expf(v[k]-mx); s += v[k]; }
      s += __shfl_xor(s,1,64); s += __shfl_xor(s,2,64);
      s += __shfl_xor(s,4,64); s += __shfl_xor(s,8,64);
      float iv = mk / s;
      s16x4 q4 = { (short)f2b(v[0]*iv), (short)f2b(v[1]*iv),
                   (short)f2b(v[2]*iv), (short)f2b(v[3]*iv) };
      *(s16x4*)&qzb[(size_t)rg*64 + c4*4] = q4;
      *(s16x4*)&qlds[row16*72 + c4*4] = q4;
    }
  }
  if(mode == 2) return;                       // uniform: no barrier crossed
  __syncthreads();
  // ---- P2 = rowsoftmax(qz @ gw^T) (waves 0-3; fixed-max exp) ----
  float fv[4];
  if(t < 256){
    bf16x8 a0 = ldb8(&qlds[l15*72 + lhi*8]);
    bf16x8 a1 = ldb8(&qlds[l15*72 + lhi*8 + 32]);
    const u16* Br = Gt2 + (size_t)(w*16 + l15)*64 + lhi*8;
    f32x4 acc = {0.f,0.f,0.f,0.f};
    acc = MFMA(a0, ldb8(Br), acc);
    acc = MFMA(a1, ldb8(Br+32), acc);
    #pragma unroll
    for(int jj=0;jj<4;jj++){
      float e = __expf(acc[jj]);
      fv[jj] = e;
      float p = g16_sum(e);
      if(l15==0) red2[(lhi*4+jj)*4 + w] = p;
    }
  }
  __syncthreads();
  if(t < 256){
    #pragma unroll
    for(int jj=0;jj<4;jj++){
      int r = lhi*4+jj;
      float s = red2[r*4+0]+red2[r*4+1]+red2[r*4+2]+red2[r*4+3];
      float iv = 1.f/s;
      P2s[r*72 + w*16 + l15] = f2b(fv[jj]*iv);
    }
  }
  __syncthreads();
  if(t < 256){
    // ---- Mg[i,a] = sum_j P2[i,j] gw[j,a]; a-quadrant per wave ----
    bf16x8 a0 = ldb8(&P2s[l15*72 + lhi*8]);
    bf16x8 a1 = ldb8(&P2s[l15*72 + lhi*8 + 32]);
    const u16* Br = Gt + (size_t)(w*16 + l15)*64 + lhi*8;
    f32x4 acc = {0.f,0.f,0.f,0.f};
    acc = MFMA(a0, ldb8(Br), acc);
    acc = MFMA(a1, ldb8(Br+32), acc);
    #pragma unroll
    for(int jj=0;jj<4;jj++)
      MgF_out[((size_t)rbase + lhi*4 + jj)*64 + w*16 + l15] = acc[jj];
  }
  // ---- phase T (all 8 waves): t1b/t1t/t2t for this tile's 16 rows; wave w = c ----
  {
    int c = w;
    size_t zc = (size_t)z*8 + c;
    bf16x8 aq0 = ldb8(&qlds[l15*72 + lhi*8]);
    bf16x8 aq1 = ldb8(&qlds[l15*72 + lhi*8 + 32]);
    const u16* T4c = T4t + c*4096;
    const u16* Ttc = Tt2 + c*4096;
    #pragma unroll
    for(int s=0;s<4;s++){
      const u16* Bq = T4c + (s*16 + l15)*64 + lhi*8;
      bf16x8 tb0 = ldb8(Bq), tb1 = ldb8(Bq+32);
      const u16* Uq = Ttc + (s*16 + l15)*64 + lhi*8;
      bf16x8 ub0 = ldb8(Uq), ub1 = ldb8(Uq+32);
      f32x4 d1 = {0.f,0.f,0.f,0.f};               // t1[i][b] (row=i,col=b)
      d1 = MFMA(aq0, tb0, d1);
      d1 = MFMA(aq1, tb1, d1);
      f32x4 d2 = {0.f,0.f,0.f,0.f};               // t1t[b][i] (row=b,col=i)
      d2 = MFMA(tb0, aq0, d2);
      d2 = MFMA(tb1, aq1, d2);
      f32x4 d3 = {0.f,0.f,0.f,0.f};               // t2t[a][j] (row=a,col=j)
      d3 = MFMA(ub0, aq0, d3);
      d3 = MFMA(ub1, aq1, d3);
      #pragma unroll
      for(int jj=0;jj<4;jj++){
        int r4 = lhi*4 + jj;
        t1b[(zc*LL + itile*16 + r4)*64 + s*16 + l15]  = f2b(d1[jj]);
        t1t[(zc*64 + s*16 + r4)*LL + itile*16 + l15]  = f2b(d2[jj]);
        t2t[(zc*64 + s*16 + r4)*LL + itile*16 + l15]  = f2b(d3[jj]);
      }
    }
  }
}

// ---- kF: round-15 structure (verified 40us): t2s LDS stage + unnorm Pp +
// wave-local PpT + LDS-atomic parity row-sums (2 barriers/panel). ----
__global__ __launch_bounds__(1024) void kF(const u16* __restrict__ t1b, const u16* __restrict__ qzb,
        const u16* __restrict__ t1t, const u16* __restrict__ t2t, const float* __restrict__ mf,
        u16* __restrict__ miP, u16* __restrict__ mjP){
  extern __shared__ char smem[];
  u16*   t2s  = (u16*)smem;                    // [64][520]   66560 B
  u16*   Pp   = (u16*)(smem + 66560);          // [32][520]   33280 B (unnormalized exp)
  u16*   PpT  = (u16*)(smem + 99840);          // [16w][32][40] 40960 B (normalized, wave-local)
  float* redS2= (float*)(smem + 140800);       // [2][32]      256 B (parity row-sums)
  float* stgf = (float*)(smem + 141056);       // [2][32][68] f32 17408 B  (end 158464)
  u16*   stg  = (u16*)smem;                    // [512][72] dump (reuses t2s+Pp, 73728 B)
  int bid = blockIdx.x;
  int z = bid&7, c = (bid>>3)&7, it = bid>>6;   // it < 4
  int zc = z*8 + c;
  int t = threadIdx.x, lane = t&63, w = t>>6, l15 = lane&15, lhi = lane>>4;
  int jc0 = w*32;                               // wave's j-slice
  int h = w>>3, wr = (w>>2)&1, wc = w&3;        // mi role
  if(t < 64) redS2[t] = 0.f;
  __syncthreads();
  #pragma unroll
  for(int m=0;m<4;m++){
    int e = (m*1024 + t)*8;
    int a = e >> 9, j = e & 511;
    *(bf16x8*)&t2s[a*520 + j] = ldb8(t2t + ((size_t)zc*64 + a)*LL + j);
  }
  float mfj[2];
  mfj[0] = mf[z*LL + jc0 + l15];
  mfj[1] = mf[z*LL + jc0 + 16 + l15];
  f32x4 mj[2][4];
  #pragma unroll
  for(int jt=0;jt<2;jt++)
    #pragma unroll
    for(int bt=0;bt<4;bt++) mj[jt][bt] = (f32x4){0.f,0.f,0.f,0.f};
  u16* PpTw = PpT + w*32*40;                    // wave-local transpose buffer

  for(int ip=0; ip<4; ++ip){
    int i0g = it*128 + ip*32;
    int par = ip & 1;
    f32x4 S[2][2];
    #pragma unroll
    for(int rt=0;rt<2;rt++){ S[rt][0] = (f32x4){0,0,0,0}; S[rt][1] = (f32x4){0,0,0,0}; }
    #pragma unroll
    for(int rt=0;rt<2;rt++){
      const u16* Ar = t1b + ((size_t)zc*LL + i0g + rt*16 + l15)*64 + lhi*8;
      bf16x8 a0 = ldb8(Ar), a1 = ldb8(Ar+32);
      #pragma unroll
      for(int ct=0;ct<2;ct++){
        const u16* Br = qzb + ((size_t)z*LL + jc0 + ct*16 + l15)*64 + lhi*8;
        S[rt][ct] = MFMA(a0, ldb8(Br), S[rt][ct]);
        S[rt][ct] = MFMA(a1, ldb8(Br+32), S[rt][ct]);
      }
    }
    #pragma unroll
    for(int rt=0;rt<2;rt++)
      #pragma unroll
      for(int jj=0;jj<4;jj++){
        int rloc = rt*16 + lhi*4 + jj;
        int irow = i0g + rloc;
        float mfi = mf[z*LL + irow];
        float ps = 0.f;
        #pragma unroll
        for(int ct=0;ct<2;ct++){
          int jcol = jc0 + ct*16 + l15;
          float v = S[rt][ct][jj] - ((irow==jcol)?BIGV:0.f);
          float e = mfi * mfj[ct] * __expf(v);
          S[rt][ct][jj] = e; ps += e;
          Pp[rloc*520 + jcol] = f2b(e);        // unnormalized
        }
        ps = g16_sum(ps);
        if(l15 == 0) atomicAdd(&redS2[par*32 + rloc], ps);   // ds_add_f32, no-return
      }
    __syncthreads();                            // B1: Pp + redS2[par] complete (t2s on ip=0)
    if(t < 32) redS2[(par^1)*32 + t] = 0.f;     // zero other parity for next panel
    float ivv[2][4];
    #pragma unroll
    for(int rt=0;rt<2;rt++)
      #pragma unroll
      for(int jj=0;jj<4;jj++){
        float s = redS2[par*32 + rt*16 + lhi*4 + jj];
        ivv[rt][jj] = s > 0.f ? 1.f/s : 0.f;
      }
    #pragma unroll
    for(int rt=0;rt<2;rt++)
      #pragma unroll
      for(int ct=0;ct<2;ct++){
        s16x4 v4 = { (short)f2b(S[rt][ct][0]*ivv[rt][0]), (short)f2b(S[rt][ct][1]*ivv[rt][1]),
                     (short)f2b(S[rt][ct][2]*ivv[rt][2]), (short)f2b(S[rt][ct][3]*ivv[rt][3]) };
        *(s16x4*)&PpTw[(ct*16 + l15)*40 + rt*16 + lhi*4] = v4;
      }
    {
      f32x4 mia = {0.f,0.f,0.f,0.f};
      const u16* Ab = Pp + (wr*16 + l15)*520 + h*256 + lhi*8;
      const u16* Bb = t2s + (wc*16 + l15)*520 + h*256 + lhi*8;
      #pragma unroll
      for(int ks=0;ks<8;ks++)
        mia = MFMA(ldb8(Ab + ks*32), ldb8(Bb + ks*32), mia);
      #pragma unroll
      for(int jj=0;jj<4;jj++)
        stgf[(h*32 + wr*16 + lhi*4 + jj)*68 + wc*16 + l15] = mia[jj]*ivv[wr][jj];
    }
    {
      bf16x8 av[2];
      #pragma unroll
      for(int jt=0;jt<2;jt++)
        av[jt] = ldb8(PpTw + (jt*16 + l15)*40 + lhi*8);
      #pragma unroll
      for(int bt=0;bt<4;bt++){
        bf16x8 b = ldb8(t1t + ((size_t)zc*64 + bt*16 + l15)*LL + i0g + lhi*8);
        #pragma unroll
        for(int jt=0;jt<2;jt++) mj[jt][bt] = MFMA(av[jt], b, mj[jt][bt]);
      }
    }
    __syncthreads();                            // B2: stgf ready; Pp/t2s reads done;
                                                //     orders parity-zero vs next atomics
    if(t < 512){
      int r = t>>4, cc = t&15;
      f32x4 v0 = *(const f32x4*)&stgf[r*68 + cc*4];
      f32x4 v1 = *(const f32x4*)&stgf[(32+r)*68 + cc*4];
      s16x4 o = { (short)f2b(v0[0]+v1[0]), (short)f2b(v0[1]+v1[1]),
                  (short)f2b(v0[2]+v1[2]), (short)f2b(v0[3]+v1[3]) };
      *(s16x4*)&miP[((size_t)z*LL + i0g + r)*512 + c*64 + cc*4] = o;
    }
  }
  // ---- mj dump: single pass, stg[512][72] reuses dead t2s+Pp space ----
  #pragma unroll
  for(int jt=0;jt<2;jt++)
    #pragma unroll
    for(int bt=0;bt<4;bt++)
      #pragma unroll
      for(int jj=0;jj<4;jj++)
        stg[(jc0 + jt*16 + lhi*4 + jj)*72 + bt*16 + l15] = f2b(mj[jt][bt][jj]);
  __syncthreads();
  #pragma unroll
  for(int q=0;q<4;q++){
    int e = q*1024 + t;
    int j = e >> 3, ch = e & 7;
    *(bf16x8*)&mjP[(((size_t)(it*8 + z))*LL + j)*512 + c*64 + ch*8]
      = *(const bf16x8*)&stg[j*72 + ch*8];
  }
}

extern "C" void kernel_launch(void* const* d_in, const int* in_sizes, int n_in,
                              void* d_out, int out_size, void* d_ws, size_t ws_size,
                              hipStream_t stream) {
  const float* x       = (const float*)d_in[0];
  const int*   mask    = (const int*)d_in[1];
  const float* ternary = (const float*)d_in[2];
  const float* gw      = (const float*)d_in[3];
  float* out = (float*)d_out;

  const size_t NE = (size_t)BB*LL*64;          // 262144
  char* p = (char*)d_ws;
  auto alloc = [&](size_t bytes)->void*{
    void* r = (void*)p; p += (bytes + 255) & ~(size_t)255; return r;
  };
  float* unary   = (float*)alloc(NE*4);
  float* mf      = (float*)alloc((size_t)BB*LL*4);
  u16*   qzb     = (u16*)alloc(NE*2);
  u16*   t1b     = (u16*)alloc((size_t)BB*HH*LL*64*2);   // 4.2 MB
  u16*   t1t     = (u16*)alloc((size_t)BB*HH*LL*64*2);   // 4.2 MB
  u16*   t2t     = (u16*)alloc((size_t)BB*HH*LL*64*2);   // 4.2 MB
  float* MgF     = (float*)alloc(NE*4);                  // 1 MB
  u16*   miP     = (u16*)alloc((size_t)BB*LL*512*2);     // 4.2 MB
  u16*   mjP     = (u16*)alloc((size_t)32*LL*512*2);     // 16.8 MB (4 it-partials)
  u16*   T4t     = (u16*)alloc(32768*2);
  u16*   Tt2     = (u16*)alloc(32768*2);
  u16*   Gt      = (u16*)alloc(4096*2);
  u16*   Gt2     = (u16*)alloc(4096*2);

  const int KF_LDS = 158464;  // t2s + Pp + PpT + redS2 + stgf
  hipFuncSetAttribute(reinterpret_cast<const void*>(kF),
                      hipFuncAttributeMaxDynamicSharedMemorySize, KF_LDS);

  kp_prep<<<128, 256, 0, stream>>>(ternary, gw, T4t, Tt2, Gt, Gt2);
  kCA<<<256, 512, 0, stream>>>(x, mask, miP, mjP, MgF, unary, mf, Gt2, Gt,
                               T4t, Tt2, qzb, MgF, out, t1b, t1t, t2t, 0);
  for(int it=0; it<4; ++it){
    kF<<<256, 1024, KF_LDS, stream>>>(t1b, qzb, t1t, t2t, mf, miP, mjP);
    kCA<<<256, 512, 0, stream>>>(x, mask, miP, mjP, MgF, unary, mf, Gt2, Gt,
                                 T4t, Tt2, qzb, MgF, out, t1b, t1t, t2t, (it==3) ? 2 : 1);
  }
}

// Round 21
// 199.448 us; speedup vs baseline: 1.4487x; 1.0435x over previous
//
#include <hip/hip_runtime.h>

#define BB 8
#define LL 512
#define HH 8
#define BIGV (1e9f)

typedef unsigned short u16;
typedef __attribute__((ext_vector_type(8))) short bf16x8;
typedef __attribute__((ext_vector_type(4))) short s16x4;
typedef __attribute__((ext_vector_type(4))) float f32x4;
typedef __attribute__((ext_vector_type(2))) unsigned int u32x2;

#define MFMA(a,b,c) __builtin_amdgcn_mfma_f32_16x16x32_bf16(a,b,c,0,0,0)

__device__ __forceinline__ u16 f2b(float f){
  unsigned u = __float_as_uint(f);
  u = (u + 0x7fffu + ((u>>16)&1u)) >> 16;
  return (u16)u;
}
__device__ __forceinline__ float b2f(u16 s){ return __uint_as_float(((unsigned)s)<<16); }
__device__ __forceinline__ bf16x8 ldb8(const u16* p){ return *(const bf16x8*)p; }
__device__ __forceinline__ s16x4 ld4nt(const u16* p){ return __builtin_nontemporal_load((const s16x4*)p); }
// packed RNE f32->bf16 pair: dst.lo = bf16(lo), dst.hi = bf16(hi). Same
// rounding as f2b (RNE) -> bit-identical outputs, 1 inst instead of ~10.
__device__ __forceinline__ unsigned cvtpk(float lo, float hi){
  unsigned r;
  asm("v_cvt_pk_bf16_f32 %0, %1, %2" : "=v"(r) : "v"(lo), "v"(hi));
  return r;
}

__device__ __forceinline__ float g16_sum(float v){
  v += __shfl_xor(v,1,64); v += __shfl_xor(v,2,64);
  v += __shfl_xor(v,4,64); v += __shfl_xor(v,8,64);
  return v;
}

// ---- tables: T4t[c][b][a], Tt2[c][a][b], Gt[a][j], Gt2[j][a] ----
__global__ void kp_prep(const float* __restrict__ T, const float* __restrict__ gw,
                        u16* __restrict__ T4t, u16* __restrict__ Tt2,
                        u16* __restrict__ Gt, u16* __restrict__ Gt2){
  int idx = blockIdx.x*256 + threadIdx.x;   // < 32768
  { int c=idx>>12, b=(idx>>6)&63, a=idx&63; T4t[idx] = f2b(T[(a*64+b)*8+c]); }
  { int c=idx>>12, a=(idx>>6)&63, b=idx&63; Tt2[idx] = f2b(T[(a*64+b)*8+c]); }
  if(idx < 4096){
    int a=idx>>6, j=idx&63;
    Gt[idx]  = f2b(gw[j*64+a]);   // Gt[a][j]
    Gt2[idx] = f2b(gw[idx]);      // Gt2[j][a]
  }
}

// ---- kCA: fused [new_qz] + [row softmax] + [P2/Mg] + [t1b/t1t/t2t production] ----
__global__ __launch_bounds__(512) void kCA(const float* __restrict__ x, const int* __restrict__ mask,
      const u16* __restrict__ miP, const u16* __restrict__ mjP, const float* __restrict__ MgF_in,
      float* __restrict__ unary, float* __restrict__ mf,
      const u16* __restrict__ Gt2, const u16* __restrict__ Gt,
      const u16* __restrict__ T4t, const u16* __restrict__ Tt2,
      u16* __restrict__ qzb, float* __restrict__ MgF_out, float* __restrict__ out,
      u16* __restrict__ t1b, u16* __restrict__ t1t, u16* __restrict__ t2t, int mode){
  __shared__ u16 qlds[16*72];
  __shared__ u16 P2s[16*72];
  __shared__ float red2[16*4];
  int bid = blockIdx.x; int z = bid & 7, itile = bid >> 3;   // z-affine for XCD L2
  int t = threadIdx.x, lane = t&63, w = t>>6, l15 = lane&15, lhi = lane>>4;
  int rbase = z*LL + itile*16;
  if(t < 256){
    int row16 = t>>4, c4 = t&15;
    int rg = rbase + row16;
    float v[4]; float mk;
    if(mode == 0){
      mk = (mask[rg] != 0) ? 1.f : 0.f;
      if(c4 == 0) mf[rg] = mk;
      int pos = rg & (LL-1);
      #pragma unroll
      for(int k=0;k<4;k++){
        int d = c4*4 + k;
        float div = __expf(-(float)(d & ~1) * 0.14391156962f);  // ln(10000)/64
        float arg = (float)pos * div;
        float pe = (d & 1) ? cosf(arg) : sinf(arg);
        v[k] = (x[(size_t)rg*64 + d] + pe) * mk;
      }
      *(f32x4*)&unary[(size_t)rg*64 + c4*4] = (f32x4){v[0],v[1],v[2],v[3]};
    } else {
      mk = mf[rg];
      f32x4 acc = *(const f32x4*)&MgF_in[(size_t)rg*64 + c4*4];
      #pragma unroll
      for(int c=0;c<8;c++){
        s16x4 vv = ld4nt(&miP[(size_t)rg*512 + c*64 + c4*4]);
        acc[0]+=b2f((u16)vv[0]); acc[1]+=b2f((u16)vv[1]);
        acc[2]+=b2f((u16)vv[2]); acc[3]+=b2f((u16)vv[3]);
      }
      #pragma unroll
      for(int s=0;s<4;s++)
        #pragma unroll
        for(int c=0;c<8;c++){
          s16x4 vv = ld4nt(&mjP[(((size_t)(s*8+z))*LL + itile*16 + row16)*512 + c*64 + c4*4]);
          acc[0]+=b2f((u16)vv[0]); acc[1]+=b2f((u16)vv[1]);
          acc[2]+=b2f((u16)vv[2]); acc[3]+=b2f((u16)vv[3]);
        }
      f32x4 u0 = *(const f32x4*)&unary[(size_t)rg*64 + c4*4];
      #pragma unroll
      for(int k=0;k<4;k++) v[k] = (u0[k] + acc[k]) * mk;
    }
    if(mode == 2){
      *(f32x4*)&out[(size_t)rg*64 + c4*4] = (f32x4){v[0],v[1],v[2],v[3]};
    } else {
      // in-register row softmax: 16 lanes per row (group = c4)
      float mx = fmaxf(fmaxf(v[0],v[1]), fmaxf(v[2],v[3]));
      mx = fmaxf(mx, __shfl_xor(mx,1,64));
      mx = fmaxf(mx, __shfl_xor(mx,2,64));
      mx = fmaxf(mx, __shfl_xor(mx,4,64));
      mx = fmaxf(mx, __shfl_xor(mx,8,64));
      float s = 0.f;
      #pragma unroll
      for(int k=0;k<4;k++){ v[k] = __expf(v[k]-mx); s += v[k]; }
      s += __shfl_xor(s,1,64); s += __shfl_xor(s,2,64);
      s += __shfl_xor(s,4,64); s += __shfl_xor(s,8,64);
      float iv = mk / s;
      u32x2 q4;
      q4[0] = cvtpk(v[0]*iv, v[1]*iv);
      q4[1] = cvtpk(v[2]*iv, v[3]*iv);
      *(u32x2*)&qzb[(size_t)rg*64 + c4*4] = q4;
      *(u32x2*)&qlds[row16*72 + c4*4] = q4;
    }
  }
  if(mode == 2) return;                       // uniform: no barrier crossed
  __syncthreads();
  // ---- P2 = rowsoftmax(qz @ gw^T) (waves 0-3; fixed-max exp) ----
  float fv[4];
  if(t < 256){
    bf16x8 a0 = ldb8(&qlds[l15*72 + lhi*8]);
    bf16x8 a1 = ldb8(&qlds[l15*72 + lhi*8 + 32]);
    const u16* Br = Gt2 + (size_t)(w*16 + l15)*64 + lhi*8;
    f32x4 acc = {0.f,0.f,0.f,0.f};
    acc = MFMA(a0, ldb8(Br), acc);
    acc = MFMA(a1, ldb8(Br+32), acc);
    #pragma unroll
    for(int jj=0;jj<4;jj++){
      float e = __expf(acc[jj]);
      fv[jj] = e;
      float p = g16_sum(e);
      if(l15==0) red2[(lhi*4+jj)*4 + w] = p;
    }
  }
  __syncthreads();
  if(t < 256){
    #pragma unroll
    for(int jj=0;jj<4;jj++){
      int r = lhi*4+jj;
      float s = red2[r*4+0]+red2[r*4+1]+red2[r*4+2]+red2[r*4+3];
      float iv = 1.f/s;
      P2s[r*72 + w*16 + l15] = f2b(fv[jj]*iv);
    }
  }
  __syncthreads();
  if(t < 256){
    // ---- Mg[i,a] = sum_j P2[i,j] gw[j,a]; a-quadrant per wave ----
    bf16x8 a0 = ldb8(&P2s[l15*72 + lhi*8]);
    bf16x8 a1 = ldb8(&P2s[l15*72 + lhi*8 + 32]);
    const u16* Br = Gt + (size_t)(w*16 + l15)*64 + lhi*8;
    f32x4 acc = {0.f,0.f,0.f,0.f};
    acc = MFMA(a0, ldb8(Br), acc);
    acc = MFMA(a1, ldb8(Br+32), acc);
    #pragma unroll
    for(int jj=0;jj<4;jj++)
      MgF_out[((size_t)rbase + lhi*4 + jj)*64 + w*16 + l15] = acc[jj];
  }
  // ---- phase T (all 8 waves): t1b/t1t/t2t for this tile's 16 rows; wave w = c ----
  {
    int c = w;
    size_t zc = (size_t)z*8 + c;
    bf16x8 aq0 = ldb8(&qlds[l15*72 + lhi*8]);
    bf16x8 aq1 = ldb8(&qlds[l15*72 + lhi*8 + 32]);
    const u16* T4c = T4t + c*4096;
    const u16* Ttc = Tt2 + c*4096;
    #pragma unroll
    for(int s=0;s<4;s++){
      const u16* Bq = T4c + (s*16 + l15)*64 + lhi*8;
      bf16x8 tb0 = ldb8(Bq), tb1 = ldb8(Bq+32);
      const u16* Uq = Ttc + (s*16 + l15)*64 + lhi*8;
      bf16x8 ub0 = ldb8(Uq), ub1 = ldb8(Uq+32);
      f32x4 d1 = {0.f,0.f,0.f,0.f};               // t1[i][b] (row=i,col=b)
      d1 = MFMA(aq0, tb0, d1);
      d1 = MFMA(aq1, tb1, d1);
      f32x4 d2 = {0.f,0.f,0.f,0.f};               // t1t[b][i] (row=b,col=i)
      d2 = MFMA(tb0, aq0, d2);
      d2 = MFMA(tb1, aq1, d2);
      f32x4 d3 = {0.f,0.f,0.f,0.f};               // t2t[a][j] (row=a,col=j)
      d3 = MFMA(ub0, aq0, d3);
      d3 = MFMA(ub1, aq1, d3);
      #pragma unroll
      for(int jj=0;jj<4;jj++){
        int r4 = lhi*4 + jj;
        t1b[(zc*LL + itile*16 + r4)*64 + s*16 + l15]  = f2b(d1[jj]);
        t1t[(zc*64 + s*16 + r4)*LL + itile*16 + l15]  = f2b(d2[jj]);
        t2t[(zc*64 + s*16 + r4)*LL + itile*16 + l15]  = f2b(d3[jj]);
      }
    }
  }
}

// ---- kF: round-15 structure + VALU diet: Pp stored column-PERMUTED (within
// each 32-col wave slice, col ct*16+l15 lives at position l15*2+ct) so each
// (rt,jj) writes one cvt_pk'd dword instead of 2 scalar u16; t2s staging
// applies the identical permutation (K-contraction is perm-invariant when
// both MFMA operands agree). PpT/miP stores also cvt_pk-packed. ----
__global__ __launch_bounds__(1024) void kF(const u16* __restrict__ t1b, const u16* __restrict__ qzb,
        const u16* __restrict__ t1t, const u16* __restrict__ t2t, const float* __restrict__ mf,
        u16* __restrict__ miP, u16* __restrict__ mjP){
  extern __shared__ char smem[];
  u16*   t2s  = (u16*)smem;                    // [64][520]   66560 B (perm cols)
  u16*   Pp   = (u16*)(smem + 66560);          // [32][520]   33280 B (unnorm exp, perm cols)
  u16*   PpT  = (u16*)(smem + 99840);          // [16w][32][40] 40960 B (normalized, wave-local)
  float* redS2= (float*)(smem + 140800);       // [2][32]      256 B (parity row-sums)
  float* stgf = (float*)(smem + 141056);       // [2][32][68] f32 17408 B  (end 158464)
  u16*   stg  = (u16*)smem;                    // [512][72] dump (reuses t2s+Pp, 73728 B)
  int bid = blockIdx.x;
  int z = bid&7, c = (bid>>3)&7, it = bid>>6;   // it < 4
  int zc = z*8 + c;
  int t = threadIdx.x, lane = t&63, w = t>>6, l15 = lane&15, lhi = lane>>4;
  int jc0 = w*32;                               // wave's j-slice
  int h = w>>3, wr = (w>>2)&1, wc = w&3;        // mi role
  if(t < 64) redS2[t] = 0.f;
  __syncthreads();
  // ---- stage t2t[zc] -> t2s with per-32-group column permutation ----
  #pragma unroll
  for(int m=0;m<4;m++){
    int e = (m*1024 + t)*8;
    int a = e >> 9, p0 = e & 511;
    int g = p0 >> 5, qh = (p0 & 31) >> 1;        // qh in {0,4,8,12}
    const u16* src = t2t + ((size_t)zc*64 + a)*LL + g*32 + qh;
    s16x4 A  = *(const s16x4*)src;
    s16x4 Bv = *(const s16x4*)(src + 16);
    bf16x8 r = { A[0],Bv[0],A[1],Bv[1],A[2],Bv[2],A[3],Bv[3] };
    *(bf16x8*)&t2s[a*520 + p0] = r;
  }
  float mfj[2];
  mfj[0] = mf[z*LL + jc0 + l15];
  mfj[1] = mf[z*LL + jc0 + 16 + l15];
  f32x4 mj[2][4];
  #pragma unroll
  for(int jt=0;jt<2;jt++)
    #pragma unroll
    for(int bt=0;bt<4;bt++) mj[jt][bt] = (f32x4){0.f,0.f,0.f,0.f};
  u16* PpTw = PpT + w*32*40;                    // wave-local transpose buffer

  for(int ip=0; ip<4; ++ip){
    int i0g = it*128 + ip*32;
    int par = ip & 1;
    f32x4 S[2][2];
    #pragma unroll
    for(int rt=0;rt<2;rt++){ S[rt][0] = (f32x4){0,0,0,0}; S[rt][1] = (f32x4){0,0,0,0}; }
    #pragma unroll
    for(int rt=0;rt<2;rt++){
      const u16* Ar = t1b + ((size_t)zc*LL + i0g + rt*16 + l15)*64 + lhi*8;
      bf16x8 a0 = ldb8(Ar), a1 = ldb8(Ar+32);
      #pragma unroll
      for(int ct=0;ct<2;ct++){
        const u16* Br = qzb + ((size_t)z*LL + jc0 + ct*16 + l15)*64 + lhi*8;
        S[rt][ct] = MFMA(a0, ldb8(Br), S[rt][ct]);
        S[rt][ct] = MFMA(a1, ldb8(Br+32), S[rt][ct]);
      }
    }
    #pragma unroll
    for(int rt=0;rt<2;rt++)
      #pragma unroll
      for(int jj=0;jj<4;jj++){
        int rloc = rt*16 + lhi*4 + jj;
        int irow = i0g + rloc;
        float mfi = mf[z*LL + irow];
        float e0, e1;
        {
          int jcol = jc0 + l15;
          float v = S[rt][0][jj] - ((irow==jcol)?BIGV:0.f);
          e0 = mfi * mfj[0] * __expf(v);
        }
        {
          int jcol = jc0 + 16 + l15;
          float v = S[rt][1][jj] - ((irow==jcol)?BIGV:0.f);
          e1 = mfi * mfj[1] * __expf(v);
        }
        S[rt][0][jj] = e0; S[rt][1][jj] = e1;
        *(unsigned*)&Pp[rloc*520 + jc0 + l15*2] = cvtpk(e0, e1);  // packed, perm layout
        float ps = g16_sum(e0 + e1);
        if(l15 == 0) atomicAdd(&redS2[par*32 + rloc], ps);        // ds_add_f32, no-return
      }
    __syncthreads();                            // B1: Pp + redS2[par] complete (t2s on ip=0)
    if(t < 32) redS2[(par^1)*32 + t] = 0.f;     // zero other parity for next panel
    float ivv[2][4];
    #pragma unroll
    for(int rt=0;rt<2;rt++)
      #pragma unroll
      for(int jj=0;jj<4;jj++){
        float s = redS2[par*32 + rt*16 + lhi*4 + jj];
        ivv[rt][jj] = s > 0.f ? 1.f/s : 0.f;
      }
    #pragma unroll
    for(int rt=0;rt<2;rt++)
      #pragma unroll
      for(int ct=0;ct<2;ct++){
        u32x2 v2;
        v2[0] = cvtpk(S[rt][ct][0]*ivv[rt][0], S[rt][ct][1]*ivv[rt][1]);
        v2[1] = cvtpk(S[rt][ct][2]*ivv[rt][2], S[rt][ct][3]*ivv[rt][3]);
        *(u32x2*)&PpTw[(ct*16 + l15)*40 + rt*16 + lhi*4] = v2;
      }
    {
      f32x4 mia = {0.f,0.f,0.f,0.f};
      const u16* Ab = Pp + (wr*16 + l15)*520 + h*256 + lhi*8;
      const u16* Bb = t2s + (wc*16 + l15)*520 + h*256 + lhi*8;
      #pragma unroll
      for(int ks=0;ks<8;ks++)
        mia = MFMA(ldb8(Ab + ks*32), ldb8(Bb + ks*32), mia);
      #pragma unroll
      for(int jj=0;jj<4;jj++)
        stgf[(h*32 + wr*16 + lhi*4 + jj)*68 + wc*16 + l15] = mia[jj]*ivv[wr][jj];
    }
    {
      bf16x8 av[2];
      #pragma unroll
      for(int jt=0;jt<2;jt++)
        av[jt] = ldb8(PpTw + (jt*16 + l15)*40 + lhi*8);
      #pragma unroll
      for(int bt=0;bt<4;bt++){
        bf16x8 b = ldb8(t1t + ((size_t)zc*64 + bt*16 + l15)*LL + i0g + lhi*8);
        #pragma unroll
        for(int jt=0;jt<2;jt++) mj[jt][bt] = MFMA(av[jt], b, mj[jt][bt]);
      }
    }
    __syncthreads();                            // B2: stgf ready; Pp/t2s reads done;
                                                //     orders parity-zero vs next atomics
    if(t < 512){
      int r = t>>4, cc = t&15;
      f32x4 v0 = *(const f32x4*)&stgf[r*68 + cc*4];
      f32x4 v1 = *(const f32x4*)&stgf[(32+r)*68 + cc*4];
      u32x2 o;
      o[0] = cvtpk(v0[0]+v1[0], v0[1]+v1[1]);
      o[1] = cvtpk(v0[2]+v1[2], v0[3]+v1[3]);
      *(u32x2*)&miP[((size_t)z*LL + i0g + r)*512 + c*64 + cc*4] = o;
    }
  }
  // ---- mj dump: single pass, stg[512][72] reuses dead t2s+Pp space ----
  #pragma unroll
  for(int jt=0;jt<2;jt++)
    #pragma unroll
    for(int bt=0;bt<4;bt++)
      #pragma unroll
      for(int jj=0;jj<4;jj++)
        stg[(jc0 + jt*16 + lhi*4 + jj)*72 + bt*16 + l15] = f2b(mj[jt][bt][jj]);
  __syncthreads();
  #pragma unroll
  for(int q=0;q<4;q++){
    int e = q*1024 + t;
    int j = e >> 3, ch = e & 7;
    *(bf16x8*)&mjP[(((size_t)(it*8 + z))*LL + j)*512 + c*64 + ch*8]
      = *(const bf16x8*)&stg[j*72 + ch*8];
  }
}

extern "C" void kernel_launch(void* const* d_in, const int* in_sizes, int n_in,
                              void* d_out, int out_size, void* d_ws, size_t ws_size,
                              hipStream_t stream) {
  const float* x       = (const float*)d_in[0];
  const int*   mask    = (const int*)d_in[1];
  const float* ternary = (const float*)d_in[2];
  const float* gw      = (const float*)d_in[3];
  float* out = (float*)d_out;

  const size_t NE = (size_t)BB*LL*64;          // 262144
  char* p = (char*)d_ws;
  auto alloc = [&](size_t bytes)->void*{
    void* r = (void*)p; p += (bytes + 255) & ~(size_t)255; return r;
  };
  float* unary   = (float*)alloc(NE*4);
  float* mf      = (float*)alloc((size_t)BB*LL*4);
  u16*   qzb     = (u16*)alloc(NE*2);
  u16*   t1b     = (u16*)alloc((size_t)BB*HH*LL*64*2);   // 4.2 MB
  u16*   t1t     = (u16*)alloc((size_t)BB*HH*LL*64*2);   // 4.2 MB
  u16*   t2t     = (u16*)alloc((size_t)BB*HH*LL*64*2);   // 4.2 MB
  float* MgF     = (float*)alloc(NE*4);                  // 1 MB
  u16*   miP     = (u16*)alloc((size_t)BB*LL*512*2);     // 4.2 MB
  u16*   mjP     = (u16*)alloc((size_t)32*LL*512*2);     // 16.8 MB (4 it-partials)
  u16*   T4t     = (u16*)alloc(32768*2);
  u16*   Tt2     = (u16*)alloc(32768*2);
  u16*   Gt      = (u16*)alloc(4096*2);
  u16*   Gt2     = (u16*)alloc(4096*2);

  const int KF_LDS = 158464;  // t2s + Pp + PpT + redS2 + stgf
  hipFuncSetAttribute(reinterpret_cast<const void*>(kF),
                      hipFuncAttributeMaxDynamicSharedMemorySize, KF_LDS);

  kp_prep<<<128, 256, 0, stream>>>(ternary, gw, T4t, Tt2, Gt, Gt2);
  kCA<<<256, 512, 0, stream>>>(x, mask, miP, mjP, MgF, unary, mf, Gt2, Gt,
                               T4t, Tt2, qzb, MgF, out, t1b, t1t, t2t, 0);
  for(int it=0; it<4; ++it){
    kF<<<256, 1024, KF_LDS, stream>>>(t1b, qzb, t1t, t2t, mf, miP, mjP);
    kCA<<<256, 512, 0, stream>>>(x, mask, miP, mjP, MgF, unary, mf, Gt2, Gt,
                                 T4t, Tt2, qzb, MgF, out, t1b, t1t, t2t, (it==3) ? 2 : 1);
  }
}

// Round 22
// 194.463 us; speedup vs baseline: 1.4858x; 1.0256x over previous
//
#include <hip/hip_runtime.h>

#define BB 8
#define LL 512
#define HH 8
#define BIGV (1e9f)

typedef unsigned short u16;
typedef __attribute__((ext_vector_type(8))) short bf16x8;
typedef __attribute__((ext_vector_type(4))) short s16x4;
typedef __attribute__((ext_vector_type(4))) float f32x4;
typedef __attribute__((ext_vector_type(2))) unsigned int u32x2;

#define MFMA(a,b,c) __builtin_amdgcn_mfma_f32_16x16x32_bf16(a,b,c,0,0,0)

__device__ __forceinline__ u16 f2b(float f){
  unsigned u = __float_as_uint(f);
  u = (u + 0x7fffu + ((u>>16)&1u)) >> 16;
  return (u16)u;
}
__device__ __forceinline__ float b2f(u16 s){ return __uint_as_float(((unsigned)s)<<16); }
__device__ __forceinline__ bf16x8 ldb8(const u16* p){ return *(const bf16x8*)p; }
__device__ __forceinline__ s16x4 ld4nt(const u16* p){ return __builtin_nontemporal_load((const s16x4*)p); }
// packed RNE f32->bf16 pair: dst.lo = bf16(lo), dst.hi = bf16(hi). Same
// rounding as f2b (RNE) -> bit-identical outputs, 1 inst instead of ~10.
__device__ __forceinline__ unsigned cvtpk(float lo, float hi){
  unsigned r;
  asm("v_cvt_pk_bf16_f32 %0, %1, %2" : "=v"(r) : "v"(lo), "v"(hi));
  return r;
}

__device__ __forceinline__ float g16_sum(float v){
  v += __shfl_xor(v,1,64); v += __shfl_xor(v,2,64);
  v += __shfl_xor(v,4,64); v += __shfl_xor(v,8,64);
  return v;
}

// ---- tables: T4t[c][b][a], Tt2[c][a][b], Gt[a][j], Gt2[j][a] ----
__global__ void kp_prep(const float* __restrict__ T, const float* __restrict__ gw,
                        u16* __restrict__ T4t, u16* __restrict__ Tt2,
                        u16* __restrict__ Gt, u16* __restrict__ Gt2){
  int idx = blockIdx.x*256 + threadIdx.x;   // < 32768
  { int c=idx>>12, b=(idx>>6)&63, a=idx&63; T4t[idx] = f2b(T[(a*64+b)*8+c]); }
  { int c=idx>>12, a=(idx>>6)&63, b=idx&63; Tt2[idx] = f2b(T[(a*64+b)*8+c]); }
  if(idx < 4096){
    int a=idx>>6, j=idx&63;
    Gt[idx]  = f2b(gw[j*64+a]);   // Gt[a][j]
    Gt2[idx] = f2b(gw[idx]);      // Gt2[j][a]
  }
}

// ---- kCA: fused [new_qz] + [row softmax] + [P2/Mg] + [t1b/t1t/t2t production] ----
__global__ __launch_bounds__(512) void kCA(const float* __restrict__ x, const int* __restrict__ mask,
      const u16* __restrict__ miP, const u16* __restrict__ mjP, const float* __restrict__ MgF_in,
      float* __restrict__ unary, float* __restrict__ mf,
      const u16* __restrict__ Gt2, const u16* __restrict__ Gt,
      const u16* __restrict__ T4t, const u16* __restrict__ Tt2,
      u16* __restrict__ qzb, float* __restrict__ MgF_out, float* __restrict__ out,
      u16* __restrict__ t1b, u16* __restrict__ t1t, u16* __restrict__ t2t, int mode){
  __shared__ u16 qlds[16*72];
  __shared__ u16 P2s[16*72];
  __shared__ float red2[16*4];
  int bid = blockIdx.x; int z = bid & 7, itile = bid >> 3;   // z-affine for XCD L2
  int t = threadIdx.x, lane = t&63, w = t>>6, l15 = lane&15, lhi = lane>>4;
  int rbase = z*LL + itile*16;
  if(t < 256){
    int row16 = t>>4, c4 = t&15;
    int rg = rbase + row16;
    float v[4]; float mk;
    if(mode == 0){
      mk = (mask[rg] != 0) ? 1.f : 0.f;
      if(c4 == 0) mf[rg] = mk;
      int pos = rg & (LL-1);
      #pragma unroll
      for(int k=0;k<4;k++){
        int d = c4*4 + k;
        float div = __expf(-(float)(d & ~1) * 0.14391156962f);  // ln(10000)/64
        float arg = (float)pos * div;
        float pe = (d & 1) ? cosf(arg) : sinf(arg);
        v[k] = (x[(size_t)rg*64 + d] + pe) * mk;
      }
      *(f32x4*)&unary[(size_t)rg*64 + c4*4] = (f32x4){v[0],v[1],v[2],v[3]};
    } else {
      mk = mf[rg];
      f32x4 acc = *(const f32x4*)&MgF_in[(size_t)rg*64 + c4*4];
      #pragma unroll
      for(int c=0;c<8;c++){
        s16x4 vv = ld4nt(&miP[(size_t)rg*512 + c*64 + c4*4]);
        acc[0]+=b2f((u16)vv[0]); acc[1]+=b2f((u16)vv[1]);
        acc[2]+=b2f((u16)vv[2]); acc[3]+=b2f((u16)vv[3]);
      }
      #pragma unroll
      for(int s=0;s<4;s++)
        #pragma unroll
        for(int c=0;c<8;c++){
          s16x4 vv = ld4nt(&mjP[(((size_t)(s*8+z))*LL + itile*16 + row16)*512 + c*64 + c4*4]);
          acc[0]+=b2f((u16)vv[0]); acc[1]+=b2f((u16)vv[1]);
          acc[2]+=b2f((u16)vv[2]); acc[3]+=b2f((u16)vv[3]);
        }
      f32x4 u0 = *(const f32x4*)&unary[(size_t)rg*64 + c4*4];
      #pragma unroll
      for(int k=0;k<4;k++) v[k] = (u0[k] + acc[k]) * mk;
    }
    if(mode == 2){
      *(f32x4*)&out[(size_t)rg*64 + c4*4] = (f32x4){v[0],v[1],v[2],v[3]};
    } else {
      // in-register row softmax: 16 lanes per row (group = c4)
      float mx = fmaxf(fmaxf(v[0],v[1]), fmaxf(v[2],v[3]));
      mx = fmaxf(mx, __shfl_xor(mx,1,64));
      mx = fmaxf(mx, __shfl_xor(mx,2,64));
      mx = fmaxf(mx, __shfl_xor(mx,4,64));
      mx = fmaxf(mx, __shfl_xor(mx,8,64));
      float s = 0.f;
      #pragma unroll
      for(int k=0;k<4;k++){ v[k] = __expf(v[k]-mx); s += v[k]; }
      s += __shfl_xor(s,1,64); s += __shfl_xor(s,2,64);
      s += __shfl_xor(s,4,64); s += __shfl_xor(s,8,64);
      float iv = mk / s;
      u32x2 q4;
      q4[0] = cvtpk(v[0]*iv, v[1]*iv);
      q4[1] = cvtpk(v[2]*iv, v[3]*iv);
      *(u32x2*)&qzb[(size_t)rg*64 + c4*4] = q4;
      *(u32x2*)&qlds[row16*72 + c4*4] = q4;
    }
  }
  if(mode == 2) return;                       // uniform: no barrier crossed
  __syncthreads();
  // ---- P2 = rowsoftmax(qz @ gw^T) (waves 0-3; fixed-max exp) ----
  float fv[4];
  if(t < 256){
    bf16x8 a0 = ldb8(&qlds[l15*72 + lhi*8]);
    bf16x8 a1 = ldb8(&qlds[l15*72 + lhi*8 + 32]);
    const u16* Br = Gt2 + (size_t)(w*16 + l15)*64 + lhi*8;
    f32x4 acc = {0.f,0.f,0.f,0.f};
    acc = MFMA(a0, ldb8(Br), acc);
    acc = MFMA(a1, ldb8(Br+32), acc);
    #pragma unroll
    for(int jj=0;jj<4;jj++){
      float e = __expf(acc[jj]);
      fv[jj] = e;
      float p = g16_sum(e);
      if(l15==0) red2[(lhi*4+jj)*4 + w] = p;
    }
  }
  __syncthreads();
  if(t < 256){
    #pragma unroll
    for(int jj=0;jj<4;jj++){
      int r = lhi*4+jj;
      float s = red2[r*4+0]+red2[r*4+1]+red2[r*4+2]+red2[r*4+3];
      float iv = 1.f/s;
      P2s[r*72 + w*16 + l15] = f2b(fv[jj]*iv);
    }
  }
  __syncthreads();
  if(t < 256){
    // ---- Mg[i,a] = sum_j P2[i,j] gw[j,a]; a-quadrant per wave ----
    bf16x8 a0 = ldb8(&P2s[l15*72 + lhi*8]);
    bf16x8 a1 = ldb8(&P2s[l15*72 + lhi*8 + 32]);
    const u16* Br = Gt + (size_t)(w*16 + l15)*64 + lhi*8;
    f32x4 acc = {0.f,0.f,0.f,0.f};
    acc = MFMA(a0, ldb8(Br), acc);
    acc = MFMA(a1, ldb8(Br+32), acc);
    #pragma unroll
    for(int jj=0;jj<4;jj++)
      MgF_out[((size_t)rbase + lhi*4 + jj)*64 + w*16 + l15] = acc[jj];
  }
  // ---- phase T (all 8 waves): t1b/t1t/t2t for this tile's 16 rows; wave w = c ----
  {
    int c = w;
    size_t zc = (size_t)z*8 + c;
    bf16x8 aq0 = ldb8(&qlds[l15*72 + lhi*8]);
    bf16x8 aq1 = ldb8(&qlds[l15*72 + lhi*8 + 32]);
    const u16* T4c = T4t + c*4096;
    const u16* Ttc = Tt2 + c*4096;
    #pragma unroll
    for(int s=0;s<4;s++){
      const u16* Bq = T4c + (s*16 + l15)*64 + lhi*8;
      bf16x8 tb0 = ldb8(Bq), tb1 = ldb8(Bq+32);
      const u16* Uq = Ttc + (s*16 + l15)*64 + lhi*8;
      bf16x8 ub0 = ldb8(Uq), ub1 = ldb8(Uq+32);
      f32x4 d1 = {0.f,0.f,0.f,0.f};               // t1[i][b] (row=i,col=b)
      d1 = MFMA(aq0, tb0, d1);
      d1 = MFMA(aq1, tb1, d1);
      f32x4 d2 = {0.f,0.f,0.f,0.f};               // t1t[b][i] (row=b,col=i)
      d2 = MFMA(tb0, aq0, d2);
      d2 = MFMA(tb1, aq1, d2);
      f32x4 d3 = {0.f,0.f,0.f,0.f};               // t2t[a][j] (row=a,col=j)
      d3 = MFMA(ub0, aq0, d3);
      d3 = MFMA(ub1, aq1, d3);
      #pragma unroll
      for(int jj=0;jj<4;jj++){
        int r4 = lhi*4 + jj;
        t1b[(zc*LL + itile*16 + r4)*64 + s*16 + l15]  = f2b(d1[jj]);
        t1t[(zc*64 + s*16 + r4)*LL + itile*16 + l15]  = f2b(d2[jj]);
        t2t[(zc*64 + s*16 + r4)*LL + itile*16 + l15]  = f2b(d3[jj]);
      }
    }
  }
}

// ---- kF: round-21 structure + vectorized stgf: layout [2][8][col][jj] so the
// mi D-fragment store is one ds_write_b128 (was 4 scalar b32); reader remaps
// to two contiguous f32x4 loads + 4 wave-coalesced 128B row stores. ----
__global__ __launch_bounds__(1024) void kF(const u16* __restrict__ t1b, const u16* __restrict__ qzb,
        const u16* __restrict__ t1t, const u16* __restrict__ t2t, const float* __restrict__ mf,
        u16* __restrict__ miP, u16* __restrict__ mjP){
  extern __shared__ char smem[];
  u16*   t2s  = (u16*)smem;                    // [64][520]   66560 B (perm cols)
  u16*   Pp   = (u16*)(smem + 66560);          // [32][520]   33280 B (unnorm exp, perm cols)
  u16*   PpT  = (u16*)(smem + 99840);          // [16w][32][40] 40960 B (normalized, wave-local)
  float* redS2= (float*)(smem + 140800);       // [2][32]      256 B (parity row-sums)
  float* stgf = (float*)(smem + 141056);       // [2][8][68][4] f32 17408 B  (end 158464)
  u16*   stg  = (u16*)smem;                    // [512][72] dump (reuses t2s+Pp, 73728 B)
  int bid = blockIdx.x;
  int z = bid&7, c = (bid>>3)&7, it = bid>>6;   // it < 4
  int zc = z*8 + c;
  int t = threadIdx.x, lane = t&63, w = t>>6, l15 = lane&15, lhi = lane>>4;
  int jc0 = w*32;                               // wave's j-slice
  int h = w>>3, wr = (w>>2)&1, wc = w&3;        // mi role
  if(t < 64) redS2[t] = 0.f;
  __syncthreads();
  // ---- stage t2t[zc] -> t2s with per-32-group column permutation ----
  #pragma unroll
  for(int m=0;m<4;m++){
    int e = (m*1024 + t)*8;
    int a = e >> 9, p0 = e & 511;
    int g = p0 >> 5, qh = (p0 & 31) >> 1;        // qh in {0,4,8,12}
    const u16* src = t2t + ((size_t)zc*64 + a)*LL + g*32 + qh;
    s16x4 A  = *(const s16x4*)src;
    s16x4 Bv = *(const s16x4*)(src + 16);
    bf16x8 r = { A[0],Bv[0],A[1],Bv[1],A[2],Bv[2],A[3],Bv[3] };
    *(bf16x8*)&t2s[a*520 + p0] = r;
  }
  float mfj[2];
  mfj[0] = mf[z*LL + jc0 + l15];
  mfj[1] = mf[z*LL + jc0 + 16 + l15];
  f32x4 mj[2][4];
  #pragma unroll
  for(int jt=0;jt<2;jt++)
    #pragma unroll
    for(int bt=0;bt<4;bt++) mj[jt][bt] = (f32x4){0.f,0.f,0.f,0.f};
  u16* PpTw = PpT + w*32*40;                    // wave-local transpose buffer

  for(int ip=0; ip<4; ++ip){
    int i0g = it*128 + ip*32;
    int par = ip & 1;
    f32x4 S[2][2];
    #pragma unroll
    for(int rt=0;rt<2;rt++){ S[rt][0] = (f32x4){0,0,0,0}; S[rt][1] = (f32x4){0,0,0,0}; }
    #pragma unroll
    for(int rt=0;rt<2;rt++){
      const u16* Ar = t1b + ((size_t)zc*LL + i0g + rt*16 + l15)*64 + lhi*8;
      bf16x8 a0 = ldb8(Ar), a1 = ldb8(Ar+32);
      #pragma unroll
      for(int ct=0;ct<2;ct++){
        const u16* Br = qzb + ((size_t)z*LL + jc0 + ct*16 + l15)*64 + lhi*8;
        S[rt][ct] = MFMA(a0, ldb8(Br), S[rt][ct]);
        S[rt][ct] = MFMA(a1, ldb8(Br+32), S[rt][ct]);
      }
    }
    #pragma unroll
    for(int rt=0;rt<2;rt++)
      #pragma unroll
      for(int jj=0;jj<4;jj++){
        int rloc = rt*16 + lhi*4 + jj;
        int irow = i0g + rloc;
        float mfi = mf[z*LL + irow];
        float e0, e1;
        {
          int jcol = jc0 + l15;
          float v = S[rt][0][jj] - ((irow==jcol)?BIGV:0.f);
          e0 = mfi * mfj[0] * __expf(v);
        }
        {
          int jcol = jc0 + 16 + l15;
          float v = S[rt][1][jj] - ((irow==jcol)?BIGV:0.f);
          e1 = mfi * mfj[1] * __expf(v);
        }
        S[rt][0][jj] = e0; S[rt][1][jj] = e1;
        *(unsigned*)&Pp[rloc*520 + jc0 + l15*2] = cvtpk(e0, e1);  // packed, perm layout
        float ps = g16_sum(e0 + e1);
        if(l15 == 0) atomicAdd(&redS2[par*32 + rloc], ps);        // ds_add_f32, no-return
      }
    __syncthreads();                            // B1: Pp + redS2[par] complete (t2s on ip=0)
    if(t < 32) redS2[(par^1)*32 + t] = 0.f;     // zero other parity for next panel
    float ivv[2][4];
    #pragma unroll
    for(int rt=0;rt<2;rt++)
      #pragma unroll
      for(int jj=0;jj<4;jj++){
        float s = redS2[par*32 + rt*16 + lhi*4 + jj];
        ivv[rt][jj] = s > 0.f ? 1.f/s : 0.f;
      }
    #pragma unroll
    for(int rt=0;rt<2;rt++)
      #pragma unroll
      for(int ct=0;ct<2;ct++){
        u32x2 v2;
        v2[0] = cvtpk(S[rt][ct][0]*ivv[rt][0], S[rt][ct][1]*ivv[rt][1]);
        v2[1] = cvtpk(S[rt][ct][2]*ivv[rt][2], S[rt][ct][3]*ivv[rt][3]);
        *(u32x2*)&PpTw[(ct*16 + l15)*40 + rt*16 + lhi*4] = v2;
      }
    {
      f32x4 mia = {0.f,0.f,0.f,0.f};
      const u16* Ab = Pp + (wr*16 + l15)*520 + h*256 + lhi*8;
      const u16* Bb = t2s + (wc*16 + l15)*520 + h*256 + lhi*8;
      #pragma unroll
      for(int ks=0;ks<8;ks++)
        mia = MFMA(ldb8(Ab + ks*32), ldb8(Bb + ks*32), mia);
      // one b128 write: stgf[h][wr*4+lhi][wc*16+l15][0..3]
      f32x4 dv = { mia[0]*ivv[wr][0], mia[1]*ivv[wr][1],
                   mia[2]*ivv[wr][2], mia[3]*ivv[wr][3] };
      *(f32x4*)&stgf[(((h*8 + wr*4 + lhi)*68) + wc*16 + l15)*4] = dv;
    }
    {
      bf16x8 av[2];
      #pragma unroll
      for(int jt=0;jt<2;jt++)
        av[jt] = ldb8(PpTw + (jt*16 + l15)*40 + lhi*8);
      #pragma unroll
      for(int bt=0;bt<4;bt++){
        bf16x8 b = ldb8(t1t + ((size_t)zc*64 + bt*16 + l15)*LL + i0g + lhi*8);
        #pragma unroll
        for(int jt=0;jt<2;jt++) mj[jt][bt] = MFMA(av[jt], b, mj[jt][bt]);
      }
    }
    __syncthreads();                            // B2: stgf ready; Pp/t2s reads done;
                                                //     orders parity-zero vs next atomics
    if(t < 512){
      int g2 = t>>6, col = t&63;                // rowgroup, column
      int wr2 = g2>>2, lhi2 = g2&3;
      f32x4 v0 = *(const f32x4*)&stgf[((g2)*68 + col)*4];
      f32x4 v1 = *(const f32x4*)&stgf[((8 + g2)*68 + col)*4];
      #pragma unroll
      for(int jj=0;jj<4;jj++){
        int r = wr2*16 + lhi2*4 + jj;
        miP[((size_t)z*LL + i0g + r)*512 + c*64 + col] = f2b(v0[jj]+v1[jj]);
      }
    }
  }
  // ---- mj dump: single pass, stg[512][72] reuses dead t2s+Pp space ----
  #pragma unroll
  for(int jt=0;jt<2;jt++)
    #pragma unroll
    for(int bt=0;bt<4;bt++)
      #pragma unroll
      for(int jj=0;jj<4;jj++)
        stg[(jc0 + jt*16 + lhi*4 + jj)*72 + bt*16 + l15] = f2b(mj[jt][bt][jj]);
  __syncthreads();
  #pragma unroll
  for(int q=0;q<4;q++){
    int e = q*1024 + t;
    int j = e >> 3, ch = e & 7;
    *(bf16x8*)&mjP[(((size_t)(it*8 + z))*LL + j)*512 + c*64 + ch*8]
      = *(const bf16x8*)&stg[j*72 + ch*8];
  }
}

extern "C" void kernel_launch(void* const* d_in, const int* in_sizes, int n_in,
                              void* d_out, int out_size, void* d_ws, size_t ws_size,
                              hipStream_t stream) {
  const float* x       = (const float*)d_in[0];
  const int*   mask    = (const int*)d_in[1];
  const float* ternary = (const float*)d_in[2];
  const float* gw      = (const float*)d_in[3];
  float* out = (float*)d_out;

  const size_t NE = (size_t)BB*LL*64;          // 262144
  char* p = (char*)d_ws;
  auto alloc = [&](size_t bytes)->void*{
    void* r = (void*)p; p += (bytes + 255) & ~(size_t)255; return r;
  };
  float* unary   = (float*)alloc(NE*4);
  float* mf      = (float*)alloc((size_t)BB*LL*4);
  u16*   qzb     = (u16*)alloc(NE*2);
  u16*   t1b     = (u16*)alloc((size_t)BB*HH*LL*64*2);   // 4.2 MB
  u16*   t1t     = (u16*)alloc((size_t)BB*HH*LL*64*2);   // 4.2 MB
  u16*   t2t     = (u16*)alloc((size_t)BB*HH*LL*64*2);   // 4.2 MB
  float* MgF     = (float*)alloc(NE*4);                  // 1 MB
  u16*   miP     = (u16*)alloc((size_t)BB*LL*512*2);     // 4.2 MB
  u16*   mjP     = (u16*)alloc((size_t)32*LL*512*2);     // 16.8 MB (4 it-partials)
  u16*   T4t     = (u16*)alloc(32768*2);
  u16*   Tt2     = (u16*)alloc(32768*2);
  u16*   Gt      = (u16*)alloc(4096*2);
  u16*   Gt2     = (u16*)alloc(4096*2);

  const int KF_LDS = 158464;  // t2s + Pp + PpT + redS2 + stgf
  hipFuncSetAttribute(reinterpret_cast<const void*>(kF),
                      hipFuncAttributeMaxDynamicSharedMemorySize, KF_LDS);

  kp_prep<<<128, 256, 0, stream>>>(ternary, gw, T4t, Tt2, Gt, Gt2);
  kCA<<<256, 512, 0, stream>>>(x, mask, miP, mjP, MgF, unary, mf, Gt2, Gt,
                               T4t, Tt2, qzb, MgF, out, t1b, t1t, t2t, 0);
  for(int it=0; it<4; ++it){
    kF<<<256, 1024, KF_LDS, stream>>>(t1b, qzb, t1t, t2t, mf, miP, mjP);
    kCA<<<256, 512, 0, stream>>>(x, mask, miP, mjP, MgF, unary, mf, Gt2, Gt,
                                 T4t, Tt2, qzb, MgF, out, t1b, t1t, t2t, (it==3) ? 2 : 1);
  }
}